// Round 4
// baseline (2501.444 us; speedup 1.0000x reference)
//
#include <hip/hip_runtime.h>
#include <math.h>

#define NN 50000
#define NE 800000
#define NR 16
#define NEP_MAX (NE + NR * 16)   // type groups padded to multiples of 16

typedef __attribute__((ext_vector_type(8))) short short8;
typedef __attribute__((ext_vector_type(4))) float floatx4;

__device__ __forceinline__ unsigned short f2bf(float x) {
    unsigned int u = __float_as_uint(x);
    u += 0x7fffu + ((u >> 16) & 1u);
    return (unsigned short)(u >> 16);
}
__device__ __forceinline__ float bf2f(unsigned short s) {
    return __uint_as_float(((unsigned int)s) << 16);
}

// ---------------------------------------------------------------------------
// K1: build MFMA-fragment-layout weights (bf16) + attention bias
//   wfrag[t][nt][lane][j] = relw[t][k][n],  k=(lane>>4)*8+j, n=(lane&15)+16*nt
//   afrag[ks][nt][lane][j] = A_w[ks*32+k][n]
//   aproj[t][j] = A_b[j] + sum_k attn_emb[t,k]*A_w[64+k, j]
// Linear index for [t][nt][lane][j] = t*1024 + nt*512 + lane*8 + j.
// ---------------------------------------------------------------------------
__global__ void k_prep(const float* __restrict__ weight, const float* __restrict__ w_comp,
                       const float* __restrict__ A_w, const float* __restrict__ A_b,
                       const float* __restrict__ attn_emb,
                       unsigned short* __restrict__ wfrag, unsigned short* __restrict__ afrag,
                       float* __restrict__ aproj) {
    int g = blockIdx.x * blockDim.x + threadIdx.x;
    if (g < 16 * 2 * 64 * 8) {                 // wfrag: 16384 (1024 per type)
        int t = g >> 10, rest = g & 1023;      // FIXED: was g>>11 / &2047 (scrambled W)
        int nt = rest >> 9, l = (rest >> 3) & 63, j = rest & 7;
        int k = (l >> 4) * 8 + j, n = (l & 15) + 16 * nt;
        float acc = 0.f;
#pragma unroll
        for (int b = 0; b < 4; b++) acc += w_comp[t * 4 + b] * weight[b * 1024 + k * 32 + n];
        wfrag[g] = f2bf(acc);
    }
    if (g < 2 * 2 * 64 * 8) {                  // afrag: 2048 (1024 per ks)
        int ks = g >> 10, rest = g & 1023;
        int nt = rest >> 9, l = (rest >> 3) & 63, j = rest & 7;
        int k = ks * 32 + (l >> 4) * 8 + j, n = (l & 15) + 16 * nt;
        afrag[g] = f2bf(A_w[k * 32 + n]);
    }
    if (g < 16 * 32) {                         // aproj: 512
        int t = g >> 5, j = g & 31;
        float acc = A_b[j];
#pragma unroll
        for (int k = 0; k < 32; k++) acc += attn_emb[t * 32 + k] * A_w[(64 + k) * 32 + j];
        aproj[g] = acc;
    }
}

// ---------------------------------------------------------------------------
// K2: init_fea = concat(feat, embed[idx]) @ T -> out[:,0,:] (fp32) + bf16 copy
// ---------------------------------------------------------------------------
__global__ void k_init(const float* __restrict__ feat, const float* __restrict__ emb,
                       const float* __restrict__ T, const int* __restrict__ idx,
                       float* __restrict__ out, unsigned short* __restrict__ init_bf) {
    int i = blockIdx.x * blockDim.x + threadIdx.x;
    if (i >= NN) return;
    float v[32], acc[32];
#pragma unroll
    for (int o = 0; o < 32; o++) acc[o] = 0.f;
    const float4* fp = (const float4*)(feat + (size_t)i * 32);
#pragma unroll
    for (int q = 0; q < 8; q++) {
        float4 f = fp[q];
        v[4 * q] = f.x; v[4 * q + 1] = f.y; v[4 * q + 2] = f.z; v[4 * q + 3] = f.w;
    }
#pragma unroll
    for (int d = 0; d < 32; d++) {
        float xd = v[d];
#pragma unroll
        for (int o = 0; o < 32; o++) acc[o] += xd * T[d * 32 + o];
    }
    int row = idx[i];
    const float4* ep = (const float4*)(emb + (size_t)row * 32);
#pragma unroll
    for (int q = 0; q < 8; q++) {
        float4 f = ep[q];
        v[4 * q] = f.x; v[4 * q + 1] = f.y; v[4 * q + 2] = f.z; v[4 * q + 3] = f.w;
    }
#pragma unroll
    for (int d = 0; d < 32; d++) {
        float xd = v[d];
#pragma unroll
        for (int o = 0; o < 32; o++) acc[o] += xd * T[(32 + d) * 32 + o];
    }
    float4* op = (float4*)(out + (size_t)i * 64);
#pragma unroll
    for (int q = 0; q < 8; q++) {
        float4 f;
        f.x = acc[4 * q]; f.y = acc[4 * q + 1]; f.z = acc[4 * q + 2]; f.w = acc[4 * q + 3];
        op[q] = f;
    }
    unsigned int w[16];
#pragma unroll
    for (int q = 0; q < 16; q++)
        w[q] = (unsigned int)f2bf(acc[2 * q]) | ((unsigned int)f2bf(acc[2 * q + 1]) << 16);
    uint4* bp = (uint4*)(init_bf + (size_t)i * 32);
#pragma unroll
    for (int q = 0; q < 4; q++) {
        uint4 u; u.x = w[4 * q]; u.y = w[4 * q + 1]; u.z = w[4 * q + 2]; u.w = w[4 * q + 3];
        bp[q] = u;
    }
}

// ---------------------------------------------------------------------------
// K3: fused histograms: 50K dst bins (global atomics) + 16 type bins (LDS)
// ---------------------------------------------------------------------------
__global__ void k_hist(const int* __restrict__ ed, const int* __restrict__ et,
                       int* __restrict__ counts50, int* __restrict__ counts16) {
    __shared__ int lc[NR];
    if (threadIdx.x < NR) lc[threadIdx.x] = 0;
    __syncthreads();
    int e = blockIdx.x * blockDim.x + threadIdx.x;
    if (e < NE) {
        atomicAdd(&counts50[ed[e]], 1);
        atomicAdd(&lc[et[e]], 1);
    }
    __syncthreads();
    if (threadIdx.x < NR) atomicAdd(&counts16[threadIdx.x], lc[threadIdx.x]);
}

// ---------------------------------------------------------------------------
// K4: scans. 50K exclusive scan -> row_off + c50 cursors (1024 thr);
// thread 0 additionally: padded 16-bin scan -> toff/tend/c16.
// ---------------------------------------------------------------------------
__global__ void __launch_bounds__(1024) k_scan(const int* __restrict__ counts50,
                                               const int* __restrict__ counts16,
                                               int* __restrict__ row_off, int* __restrict__ c50,
                                               int* __restrict__ toff, int* __restrict__ tend,
                                               int* __restrict__ c16) {
    __shared__ int ls[1024];
    const int ITEMS = 49;
    int tid = threadIdx.x;
    int base = tid * ITEMS;
    int s = 0;
    for (int k = 0; k < ITEMS; k++) {
        int i = base + k;
        if (i < NN) s += counts50[i];
    }
    ls[tid] = s;
    __syncthreads();
    for (int off = 1; off < 1024; off <<= 1) {
        int v = (tid >= off) ? ls[tid - off] : 0;
        __syncthreads();
        ls[tid] += v;
        __syncthreads();
    }
    int excl = (tid == 0) ? 0 : ls[tid - 1];
    for (int k = 0; k < ITEMS; k++) {
        int i = base + k;
        if (i < NN) {
            row_off[i] = excl;
            c50[i] = excl;
            excl += counts50[i];
        }
    }
    if (tid == 1023) row_off[NN] = excl;
    if (tid == 0) {
        int acc = 0;
        for (int t = 0; t < NR; t++) {
            toff[t] = acc;
            c16[t] = acc;
            int c = counts16[t];
            tend[t] = acc + c;
            acc += ((c + 15) >> 4) << 4;   // pad to multiple of 16
        }
        toff[NR] = acc;
    }
}

// ---------------------------------------------------------------------------
// K5: fused scatter: q = type-sorted pos (padded), p = dst-sorted pos.
// tsrc/tdst indexed by q; qa_of_p[p] = q (the permutation the aggregator needs)
// ---------------------------------------------------------------------------
__global__ void k_scatter(const int* __restrict__ es, const int* __restrict__ ed,
                          const int* __restrict__ et, int* __restrict__ c16,
                          int* __restrict__ c50, int* __restrict__ tsrc,
                          int* __restrict__ tdst, int* __restrict__ qa_of_p) {
    int e = blockIdx.x * blockDim.x + threadIdx.x;
    if (e < NE) {
        int s = es[e], d = ed[e], t = et[e];
        int q = atomicAdd(&c16[t], 1);
        int p = atomicAdd(&c50[d], 1);
        tsrc[q] = s;
        tdst[q] = d;
        qa_of_p[p] = q;
    }
}

// ---------------------------------------------------------------------------
// K6: type-major MFMA kernel. One 16-edge type-pure tile per wave, no LDS.
//   msg = x @ W_t             (2x mfma 16x16x32 bf16)
//   hid = x @ A_w0 + y @ A_w1 (4x mfma) + aproj[t]
//   a = sigmoid(relu(hid) . B_w + B_b)   (16-lane butterfly reduce)
//   amsg[q] = bf16(a * msg)   -- coalesced in type order
// ---------------------------------------------------------------------------
__global__ void __launch_bounds__(256) k_msg(
    const unsigned short* __restrict__ wfrag, const unsigned short* __restrict__ afrag,
    const float* __restrict__ aproj, const float* __restrict__ B_w,
    const float* __restrict__ B_b, const int* __restrict__ toff,
    const int* __restrict__ tend, const int* __restrict__ tsrc,
    const int* __restrict__ tdst, const unsigned short* __restrict__ init_bf,
    unsigned short* __restrict__ amsg) {
    const int wave = threadIdx.x >> 6;
    const int lane = threadIdx.x & 63;
    const int q0 = (blockIdx.x * 4 + wave) * 16;
    if (q0 >= toff[NR]) return;
    int t = 0;
#pragma unroll
    for (int i = 1; i < NR; i++) t += (q0 >= toff[i]) ? 1 : 0;
    t = __builtin_amdgcn_readfirstlane(t);
    const int te = tend[t];
    const int m = lane & 15, quad = lane >> 4;
    const int qa = q0 + m;
    const bool va = qa < te;
    int src = va ? tsrc[qa] : 0;
    int dst = va ? tdst[qa] : 0;
    short8 xa = *(const short8*)(init_bf + (size_t)src * 32 + quad * 8);
    short8 ya = *(const short8*)(init_bf + (size_t)dst * 32 + quad * 8);
    short8 wb0 = *(const short8*)(wfrag + (size_t)((t * 2 + 0) * 64 + lane) * 8);
    short8 wb1 = *(const short8*)(wfrag + (size_t)((t * 2 + 1) * 64 + lane) * 8);
    short8 a00 = *(const short8*)(afrag + (size_t)((0 * 2 + 0) * 64 + lane) * 8);
    short8 a01 = *(const short8*)(afrag + (size_t)((0 * 2 + 1) * 64 + lane) * 8);
    short8 a10 = *(const short8*)(afrag + (size_t)((1 * 2 + 0) * 64 + lane) * 8);
    short8 a11 = *(const short8*)(afrag + (size_t)((1 * 2 + 1) * 64 + lane) * 8);
    floatx4 z4 = {0.f, 0.f, 0.f, 0.f};
    floatx4 mc0 = __builtin_amdgcn_mfma_f32_16x16x32_bf16(xa, wb0, z4, 0, 0, 0);
    floatx4 mc1 = __builtin_amdgcn_mfma_f32_16x16x32_bf16(xa, wb1, z4, 0, 0, 0);
    floatx4 hc0 = __builtin_amdgcn_mfma_f32_16x16x32_bf16(xa, a00, z4, 0, 0, 0);
    hc0 = __builtin_amdgcn_mfma_f32_16x16x32_bf16(ya, a10, hc0, 0, 0, 0);
    floatx4 hc1 = __builtin_amdgcn_mfma_f32_16x16x32_bf16(xa, a01, z4, 0, 0, 0);
    hc1 = __builtin_amdgcn_mfma_f32_16x16x32_bf16(ya, a11, hc1, 0, 0, 0);
    const int col = m;
    float ap0 = aproj[t * 32 + col], ap1 = aproj[t * 32 + 16 + col];
    float bw0 = B_w[col], bw1 = B_w[col + 16];
    float bb = B_b[0];
    float part[4];
#pragma unroll
    for (int r = 0; r < 4; r++)
        part[r] = fmaxf(hc0[r] + ap0, 0.f) * bw0 + fmaxf(hc1[r] + ap1, 0.f) * bw1;
#pragma unroll
    for (int s = 1; s < 16; s <<= 1) {
#pragma unroll
        for (int r = 0; r < 4; r++) part[r] += __shfl_xor(part[r], s, 64);
    }
#pragma unroll
    for (int r = 0; r < 4; r++) {
        int qe = q0 + quad * 4 + r;
        if (qe < te) {
            float a = 1.f / (1.f + __expf(-(part[r] + bb)));
            amsg[(size_t)qe * 32 + col] = f2bf(a * mc0[r]);
            amsg[(size_t)qe * 32 + col + 16] = f2bf(a * mc1[r]);
        }
    }
}

// ---------------------------------------------------------------------------
// K7: dst-major aggregation + fused self-loop GEMM + ReLU.
// 4 threads per node (8 cols each); node's edges are contiguous in p.
// ---------------------------------------------------------------------------
__global__ void __launch_bounds__(256) k_agg(
    const int* __restrict__ row_off, const int* __restrict__ qa_of_p,
    const unsigned short* __restrict__ amsg, const float* __restrict__ S,
    float* __restrict__ out) {
    int tid = threadIdx.x;
    int v = blockIdx.x * 64 + (tid >> 2);
    if (v >= NN) return;
    int c0 = (tid & 3) * 8;
    float acc[8];
#pragma unroll
    for (int j = 0; j < 8; j++) acc[j] = 0.f;
    int p0 = row_off[v], p1 = row_off[v + 1];
    for (int p = p0; p < p1; p++) {
        int q = qa_of_p[p];
        short8 mv = *(const short8*)(amsg + (size_t)q * 32 + c0);
#pragma unroll
        for (int j = 0; j < 8; j++) acc[j] += bf2f((unsigned short)mv[j]);
    }
    float x[32];
    const float4* xp = (const float4*)(out + (size_t)v * 64);
#pragma unroll
    for (int q = 0; q < 8; q++) {
        float4 f = xp[q];
        x[4 * q] = f.x; x[4 * q + 1] = f.y; x[4 * q + 2] = f.z; x[4 * q + 3] = f.w;
    }
#pragma unroll
    for (int d = 0; d < 32; d++) {
        float xd = x[d];
#pragma unroll
        for (int j = 0; j < 8; j++) acc[j] += xd * S[d * 32 + c0 + j];
    }
    float4* op = (float4*)(out + (size_t)v * 64 + 32 + c0);
#pragma unroll
    for (int q = 0; q < 2; q++) {
        float4 f;
        f.x = fmaxf(acc[4 * q], 0.f);
        f.y = fmaxf(acc[4 * q + 1], 0.f);
        f.z = fmaxf(acc[4 * q + 2], 0.f);
        f.w = fmaxf(acc[4 * q + 3], 0.f);
        op[q] = f;
    }
}

extern "C" void kernel_launch(void* const* d_in, const int* in_sizes, int n_in,
                              void* d_out, int out_size, void* d_ws, size_t ws_size,
                              hipStream_t stream) {
    const float* feat      = (const float*)d_in[0];
    const float* embed     = (const float*)d_in[1];
    const float* transform = (const float*)d_in[2];
    const float* weight    = (const float*)d_in[3];
    const float* w_comp    = (const float*)d_in[4];
    const float* self_w    = (const float*)d_in[5];
    const float* A_w       = (const float*)d_in[6];
    const float* A_b       = (const float*)d_in[7];
    const float* B_w       = (const float*)d_in[8];
    const float* B_b       = (const float*)d_in[9];
    const float* attn_emb  = (const float*)d_in[10];
    const int*   idx       = (const int*)d_in[11];
    const int*   edge_src  = (const int*)d_in[12];
    const int*   edge_dst  = (const int*)d_in[13];
    const int*   edge_type = (const int*)d_in[14];
    float* out = (float*)d_out;

    // -------- workspace layout (16B-aligned large arrays first) --------
    char* ws = (char*)d_ws;
    unsigned short* amsg    = (unsigned short*)ws;                 // NEP_MAX*32 us = 51,216,384 B
    unsigned short* init_bf = (unsigned short*)(ws + (size_t)NEP_MAX * 64);          // 3,200,000 B
    unsigned short* wfrag   = (unsigned short*)((char*)init_bf + 3200000);           // 32,768 B
    unsigned short* afrag   = (unsigned short*)((char*)wfrag + 32768);               // 4,096 B
    float*          aproj   = (float*)((char*)afrag + 4096);                         // 2,048 B
    int* ip       = (int*)((char*)aproj + 2048);
    int* toff     = ip;              ip += 32;       // 17 used
    int* tend     = ip;              ip += 16;
    int* c16      = ip;              ip += 16;
    int* counts16 = ip;              ip += 16;       // adjacent to counts50 for one memset
    int* counts50 = ip;              ip += NN;
    int* row_off  = ip;              ip += NN + 1;
    int* c50      = ip;              ip += NN;
    int* tsrc     = ip;              ip += NEP_MAX;
    int* tdst     = ip;              ip += NEP_MAX;
    int* qa_of_p  = ip;              ip += NE;       // total ~64.7 MB

    hipMemsetAsync(counts16, 0, (size_t)(16 + NN) * sizeof(int), stream);

    k_prep<<<(16384 + 255) / 256, 256, 0, stream>>>(weight, w_comp, A_w, A_b, attn_emb,
                                                    wfrag, afrag, aproj);
    k_init<<<(NN + 255) / 256, 256, 0, stream>>>(feat, embed, transform, idx, out, init_bf);
    k_hist<<<(NE + 255) / 256, 256, 0, stream>>>(edge_dst, edge_type, counts50, counts16);
    k_scan<<<1, 1024, 0, stream>>>(counts50, counts16, row_off, c50, toff, tend, c16);
    k_scatter<<<(NE + 255) / 256, 256, 0, stream>>>(edge_src, edge_dst, edge_type,
                                                    c16, c50, tsrc, tdst, qa_of_p);
    const int tiles = NEP_MAX / 16;                    // 50016
    k_msg<<<(tiles + 3) / 4, 256, 0, stream>>>(wfrag, afrag, aproj, B_w, B_b,
                                               toff, tend, tsrc, tdst, init_bf, amsg);
    k_agg<<<(NN + 63) / 64, 256, 0, stream>>>(row_off, qa_of_p, amsg, self_w, out);
}

// Round 5
// 420.972 us; speedup vs baseline: 5.9421x; 5.9421x over previous
//
#include <hip/hip_runtime.h>
#include <math.h>

#define NN 50000
#define NE 800000
#define NR 16
#define NEP_MAX (NE + NR * 16)   // type groups padded to multiples of 16

typedef __attribute__((ext_vector_type(8))) short short8;
typedef __attribute__((ext_vector_type(4))) float floatx4;

__device__ __forceinline__ unsigned short f2bf(float x) {
    unsigned int u = __float_as_uint(x);
    u += 0x7fffu + ((u >> 16) & 1u);
    return (unsigned short)(u >> 16);
}
__device__ __forceinline__ float bf2f(unsigned short s) {
    return __uint_as_float(((unsigned int)s) << 16);
}

// ---------------------------------------------------------------------------
// K1: build MFMA-fragment-layout weights (bf16) + attention bias
//   wfrag[t][nt][lane][j] = relw[t][k][n],  k=(lane>>4)*8+j, n=(lane&15)+16*nt
//   afrag[ks][nt][lane][j] = A_w[ks*32+k][n]
//   aproj[t][j] = A_b[j] + sum_k attn_emb[t,k]*A_w[64+k, j]
// Linear index for [t][nt][lane][j] = t*1024 + nt*512 + lane*8 + j.
// ---------------------------------------------------------------------------
__global__ void k_prep(const float* __restrict__ weight, const float* __restrict__ w_comp,
                       const float* __restrict__ A_w, const float* __restrict__ A_b,
                       const float* __restrict__ attn_emb,
                       unsigned short* __restrict__ wfrag, unsigned short* __restrict__ afrag,
                       float* __restrict__ aproj) {
    int g = blockIdx.x * blockDim.x + threadIdx.x;
    if (g < 16 * 2 * 64 * 8) {                 // wfrag: 16384 (1024 per type)
        int t = g >> 10, rest = g & 1023;
        int nt = rest >> 9, l = (rest >> 3) & 63, j = rest & 7;
        int k = (l >> 4) * 8 + j, n = (l & 15) + 16 * nt;
        float acc = 0.f;
#pragma unroll
        for (int b = 0; b < 4; b++) acc += w_comp[t * 4 + b] * weight[b * 1024 + k * 32 + n];
        wfrag[g] = f2bf(acc);
    }
    if (g < 2 * 2 * 64 * 8) {                  // afrag: 2048 (1024 per ks)
        int ks = g >> 10, rest = g & 1023;
        int nt = rest >> 9, l = (rest >> 3) & 63, j = rest & 7;
        int k = ks * 32 + (l >> 4) * 8 + j, n = (l & 15) + 16 * nt;
        afrag[g] = f2bf(A_w[k * 32 + n]);
    }
    if (g < 16 * 32) {                         // aproj: 512
        int t = g >> 5, j = g & 31;
        float acc = A_b[j];
#pragma unroll
        for (int k = 0; k < 32; k++) acc += attn_emb[t * 32 + k] * A_w[(64 + k) * 32 + j];
        aproj[g] = acc;
    }
}

// ---------------------------------------------------------------------------
// K2: init_fea = concat(feat, embed[idx]) @ T -> out[:,0,:] (fp32) + bf16 copy
// ---------------------------------------------------------------------------
__global__ void k_init(const float* __restrict__ feat, const float* __restrict__ emb,
                       const float* __restrict__ T, const int* __restrict__ idx,
                       float* __restrict__ out, unsigned short* __restrict__ init_bf) {
    int i = blockIdx.x * blockDim.x + threadIdx.x;
    if (i >= NN) return;
    float v[32], acc[32];
#pragma unroll
    for (int o = 0; o < 32; o++) acc[o] = 0.f;
    const float4* fp = (const float4*)(feat + (size_t)i * 32);
#pragma unroll
    for (int q = 0; q < 8; q++) {
        float4 f = fp[q];
        v[4 * q] = f.x; v[4 * q + 1] = f.y; v[4 * q + 2] = f.z; v[4 * q + 3] = f.w;
    }
#pragma unroll
    for (int d = 0; d < 32; d++) {
        float xd = v[d];
#pragma unroll
        for (int o = 0; o < 32; o++) acc[o] += xd * T[d * 32 + o];
    }
    int row = idx[i];
    const float4* ep = (const float4*)(emb + (size_t)row * 32);
#pragma unroll
    for (int q = 0; q < 8; q++) {
        float4 f = ep[q];
        v[4 * q] = f.x; v[4 * q + 1] = f.y; v[4 * q + 2] = f.z; v[4 * q + 3] = f.w;
    }
#pragma unroll
    for (int d = 0; d < 32; d++) {
        float xd = v[d];
#pragma unroll
        for (int o = 0; o < 32; o++) acc[o] += xd * T[(32 + d) * 32 + o];
    }
    float4* op = (float4*)(out + (size_t)i * 64);
#pragma unroll
    for (int q = 0; q < 8; q++) {
        float4 f;
        f.x = acc[4 * q]; f.y = acc[4 * q + 1]; f.z = acc[4 * q + 2]; f.w = acc[4 * q + 3];
        op[q] = f;
    }
    unsigned int w[16];
#pragma unroll
    for (int q = 0; q < 16; q++)
        w[q] = (unsigned int)f2bf(acc[2 * q]) | ((unsigned int)f2bf(acc[2 * q + 1]) << 16);
    uint4* bp = (uint4*)(init_bf + (size_t)i * 32);
#pragma unroll
    for (int q = 0; q < 4; q++) {
        uint4 u; u.x = w[4 * q]; u.y = w[4 * q + 1]; u.z = w[4 * q + 2]; u.w = w[4 * q + 3];
        bp[q] = u;
    }
}

// ---------------------------------------------------------------------------
// K3: fused histograms: 50K dst bins (global atomics) + 16 type bins (LDS)
// ---------------------------------------------------------------------------
__global__ void k_hist(const int* __restrict__ ed, const int* __restrict__ et,
                       int* __restrict__ counts50, int* __restrict__ counts16) {
    __shared__ int lc[NR];
    if (threadIdx.x < NR) lc[threadIdx.x] = 0;
    __syncthreads();
    int e = blockIdx.x * blockDim.x + threadIdx.x;
    if (e < NE) {
        atomicAdd(&counts50[ed[e]], 1);
        atomicAdd(&lc[et[e]], 1);
    }
    __syncthreads();
    if (threadIdx.x < NR) atomicAdd(&counts16[threadIdx.x], lc[threadIdx.x]);
}

// ---------------------------------------------------------------------------
// K4: scans. 50K exclusive scan -> row_off + c50 cursors (1024 thr);
// thread 0 additionally: padded 16-bin scan -> toff/tend/c16.
// ---------------------------------------------------------------------------
__global__ void __launch_bounds__(1024) k_scan(const int* __restrict__ counts50,
                                               const int* __restrict__ counts16,
                                               int* __restrict__ row_off, int* __restrict__ c50,
                                               int* __restrict__ toff, int* __restrict__ tend,
                                               int* __restrict__ c16) {
    __shared__ int ls[1024];
    const int ITEMS = 49;
    int tid = threadIdx.x;
    int base = tid * ITEMS;
    int s = 0;
    for (int k = 0; k < ITEMS; k++) {
        int i = base + k;
        if (i < NN) s += counts50[i];
    }
    ls[tid] = s;
    __syncthreads();
    for (int off = 1; off < 1024; off <<= 1) {
        int v = (tid >= off) ? ls[tid - off] : 0;
        __syncthreads();
        ls[tid] += v;
        __syncthreads();
    }
    int excl = (tid == 0) ? 0 : ls[tid - 1];
    for (int k = 0; k < ITEMS; k++) {
        int i = base + k;
        if (i < NN) {
            row_off[i] = excl;
            c50[i] = excl;
            excl += counts50[i];
        }
    }
    if (tid == 1023) row_off[NN] = excl;
    if (tid == 0) {
        int acc = 0;
        for (int t = 0; t < NR; t++) {
            toff[t] = acc;
            c16[t] = acc;
            int c = counts16[t];
            tend[t] = acc + c;
            acc += ((c + 15) >> 4) << 4;   // pad to multiple of 16
        }
        toff[NR] = acc;
    }
}

// ---------------------------------------------------------------------------
// K5: fused scatter with HIERARCHICAL type-bin claim (the R4 2.1ms lesson:
// per-edge global atomics on 16 addresses serialize at L2 — claim per block).
// Pass 1: LDS type histogram for this block's chunk.
// Claim:  lb[t] = atomicAdd(&c16[t], lc[t])   (16 atomics per block total)
// Pass 2: q = lb[t] + LDS-cursor; p = per-edge atomic on 50K-bin c50 (fine).
// ---------------------------------------------------------------------------
__global__ void k_scatter(const int* __restrict__ es, const int* __restrict__ ed,
                          const int* __restrict__ et, int* __restrict__ c16,
                          int* __restrict__ c50, int* __restrict__ tsrc,
                          int* __restrict__ tdst, int* __restrict__ qa_of_p) {
    const int chunk = (NE + gridDim.x - 1) / gridDim.x;
    const int start = blockIdx.x * chunk;
    const int end = min(start + chunk, NE);
    __shared__ int lc[NR], lb[NR];
    if (threadIdx.x < NR) lc[threadIdx.x] = 0;
    __syncthreads();
    for (int e = start + threadIdx.x; e < end; e += blockDim.x)
        atomicAdd(&lc[et[e]], 1);
    __syncthreads();
    if (threadIdx.x < NR) {
        lb[threadIdx.x] = atomicAdd(&c16[threadIdx.x], lc[threadIdx.x]);
        lc[threadIdx.x] = 0;
    }
    __syncthreads();
    for (int e = start + threadIdx.x; e < end; e += blockDim.x) {
        int s = es[e], d = ed[e], t = et[e];
        int q = lb[t] + atomicAdd(&lc[t], 1);
        int p = atomicAdd(&c50[d], 1);
        tsrc[q] = s;
        tdst[q] = d;
        qa_of_p[p] = q;
    }
}

// ---------------------------------------------------------------------------
// K6: type-major MFMA kernel. One 16-edge type-pure tile per wave, no LDS.
//   msg = x @ W_t             (2x mfma 16x16x32 bf16)
//   hid = x @ A_w0 + y @ A_w1 (4x mfma) + aproj[t]
//   a = sigmoid(relu(hid) . B_w + B_b)   (16-lane butterfly reduce)
//   amsg[q] = bf16(a * msg)   -- coalesced in type order
// ---------------------------------------------------------------------------
__global__ void __launch_bounds__(256) k_msg(
    const unsigned short* __restrict__ wfrag, const unsigned short* __restrict__ afrag,
    const float* __restrict__ aproj, const float* __restrict__ B_w,
    const float* __restrict__ B_b, const int* __restrict__ toff,
    const int* __restrict__ tend, const int* __restrict__ tsrc,
    const int* __restrict__ tdst, const unsigned short* __restrict__ init_bf,
    unsigned short* __restrict__ amsg) {
    const int wave = threadIdx.x >> 6;
    const int lane = threadIdx.x & 63;
    const int q0 = (blockIdx.x * 4 + wave) * 16;
    if (q0 >= toff[NR]) return;
    int t = 0;
#pragma unroll
    for (int i = 1; i < NR; i++) t += (q0 >= toff[i]) ? 1 : 0;
    t = __builtin_amdgcn_readfirstlane(t);
    const int te = tend[t];
    const int m = lane & 15, quad = lane >> 4;
    const int qa = q0 + m;
    const bool va = qa < te;
    int src = va ? tsrc[qa] : 0;
    int dst = va ? tdst[qa] : 0;
    short8 xa = *(const short8*)(init_bf + (size_t)src * 32 + quad * 8);
    short8 ya = *(const short8*)(init_bf + (size_t)dst * 32 + quad * 8);
    short8 wb0 = *(const short8*)(wfrag + (size_t)((t * 2 + 0) * 64 + lane) * 8);
    short8 wb1 = *(const short8*)(wfrag + (size_t)((t * 2 + 1) * 64 + lane) * 8);
    short8 a00 = *(const short8*)(afrag + (size_t)((0 * 2 + 0) * 64 + lane) * 8);
    short8 a01 = *(const short8*)(afrag + (size_t)((0 * 2 + 1) * 64 + lane) * 8);
    short8 a10 = *(const short8*)(afrag + (size_t)((1 * 2 + 0) * 64 + lane) * 8);
    short8 a11 = *(const short8*)(afrag + (size_t)((1 * 2 + 1) * 64 + lane) * 8);
    floatx4 z4 = {0.f, 0.f, 0.f, 0.f};
    floatx4 mc0 = __builtin_amdgcn_mfma_f32_16x16x32_bf16(xa, wb0, z4, 0, 0, 0);
    floatx4 mc1 = __builtin_amdgcn_mfma_f32_16x16x32_bf16(xa, wb1, z4, 0, 0, 0);
    floatx4 hc0 = __builtin_amdgcn_mfma_f32_16x16x32_bf16(xa, a00, z4, 0, 0, 0);
    hc0 = __builtin_amdgcn_mfma_f32_16x16x32_bf16(ya, a10, hc0, 0, 0, 0);
    floatx4 hc1 = __builtin_amdgcn_mfma_f32_16x16x32_bf16(xa, a01, z4, 0, 0, 0);
    hc1 = __builtin_amdgcn_mfma_f32_16x16x32_bf16(ya, a11, hc1, 0, 0, 0);
    const int col = m;
    float ap0 = aproj[t * 32 + col], ap1 = aproj[t * 32 + 16 + col];
    float bw0 = B_w[col], bw1 = B_w[col + 16];
    float bb = B_b[0];
    float part[4];
#pragma unroll
    for (int r = 0; r < 4; r++)
        part[r] = fmaxf(hc0[r] + ap0, 0.f) * bw0 + fmaxf(hc1[r] + ap1, 0.f) * bw1;
#pragma unroll
    for (int s = 1; s < 16; s <<= 1) {
#pragma unroll
        for (int r = 0; r < 4; r++) part[r] += __shfl_xor(part[r], s, 64);
    }
#pragma unroll
    for (int r = 0; r < 4; r++) {
        int qe = q0 + quad * 4 + r;
        if (qe < te) {
            float a = 1.f / (1.f + __expf(-(part[r] + bb)));
            amsg[(size_t)qe * 32 + col] = f2bf(a * mc0[r]);
            amsg[(size_t)qe * 32 + col + 16] = f2bf(a * mc1[r]);
        }
    }
}

// ---------------------------------------------------------------------------
// K7: dst-major aggregation + fused self-loop GEMM + ReLU.
// 4 threads per node (8 cols each); node's edges are contiguous in p.
// ---------------------------------------------------------------------------
__global__ void __launch_bounds__(256) k_agg(
    const int* __restrict__ row_off, const int* __restrict__ qa_of_p,
    const unsigned short* __restrict__ amsg, const float* __restrict__ S,
    float* __restrict__ out) {
    int tid = threadIdx.x;
    int v = blockIdx.x * 64 + (tid >> 2);
    if (v >= NN) return;
    int c0 = (tid & 3) * 8;
    float acc[8];
#pragma unroll
    for (int j = 0; j < 8; j++) acc[j] = 0.f;
    int p0 = row_off[v], p1 = row_off[v + 1];
    for (int p = p0; p < p1; p++) {
        int q = qa_of_p[p];
        short8 mv = *(const short8*)(amsg + (size_t)q * 32 + c0);
#pragma unroll
        for (int j = 0; j < 8; j++) acc[j] += bf2f((unsigned short)mv[j]);
    }
    float x[32];
    const float4* xp = (const float4*)(out + (size_t)v * 64);
#pragma unroll
    for (int q = 0; q < 8; q++) {
        float4 f = xp[q];
        x[4 * q] = f.x; x[4 * q + 1] = f.y; x[4 * q + 2] = f.z; x[4 * q + 3] = f.w;
    }
#pragma unroll
    for (int d = 0; d < 32; d++) {
        float xd = x[d];
#pragma unroll
        for (int j = 0; j < 8; j++) acc[j] += xd * S[d * 32 + c0 + j];
    }
    float4* op = (float4*)(out + (size_t)v * 64 + 32 + c0);
#pragma unroll
    for (int q = 0; q < 2; q++) {
        float4 f;
        f.x = fmaxf(acc[4 * q], 0.f);
        f.y = fmaxf(acc[4 * q + 1], 0.f);
        f.z = fmaxf(acc[4 * q + 2], 0.f);
        f.w = fmaxf(acc[4 * q + 3], 0.f);
        op[q] = f;
    }
}

extern "C" void kernel_launch(void* const* d_in, const int* in_sizes, int n_in,
                              void* d_out, int out_size, void* d_ws, size_t ws_size,
                              hipStream_t stream) {
    const float* feat      = (const float*)d_in[0];
    const float* embed     = (const float*)d_in[1];
    const float* transform = (const float*)d_in[2];
    const float* weight    = (const float*)d_in[3];
    const float* w_comp    = (const float*)d_in[4];
    const float* self_w    = (const float*)d_in[5];
    const float* A_w       = (const float*)d_in[6];
    const float* A_b       = (const float*)d_in[7];
    const float* B_w       = (const float*)d_in[8];
    const float* B_b       = (const float*)d_in[9];
    const float* attn_emb  = (const float*)d_in[10];
    const int*   idx       = (const int*)d_in[11];
    const int*   edge_src  = (const int*)d_in[12];
    const int*   edge_dst  = (const int*)d_in[13];
    const int*   edge_type = (const int*)d_in[14];
    float* out = (float*)d_out;

    // -------- workspace layout (16B-aligned large arrays first) --------
    char* ws = (char*)d_ws;
    unsigned short* amsg    = (unsigned short*)ws;                 // NEP_MAX*32 us = 51,216,384 B
    unsigned short* init_bf = (unsigned short*)(ws + (size_t)NEP_MAX * 64);          // 3,200,000 B
    unsigned short* wfrag   = (unsigned short*)((char*)init_bf + 3200000);           // 32,768 B
    unsigned short* afrag   = (unsigned short*)((char*)wfrag + 32768);               // 4,096 B
    float*          aproj   = (float*)((char*)afrag + 4096);                         // 2,048 B
    int* ip       = (int*)((char*)aproj + 2048);
    int* toff     = ip;              ip += 32;       // 17 used
    int* tend     = ip;              ip += 16;
    int* c16      = ip;              ip += 16;
    int* counts16 = ip;              ip += 16;       // adjacent to counts50 for one memset
    int* counts50 = ip;              ip += NN;
    int* row_off  = ip;              ip += NN + 1;
    int* c50      = ip;              ip += NN;
    int* tsrc     = ip;              ip += NEP_MAX;
    int* tdst     = ip;              ip += NEP_MAX;
    int* qa_of_p  = ip;              ip += NE;       // total ~64.7 MB

    hipMemsetAsync(counts16, 0, (size_t)(16 + NN) * sizeof(int), stream);

    k_prep<<<(16384 + 255) / 256, 256, 0, stream>>>(weight, w_comp, A_w, A_b, attn_emb,
                                                    wfrag, afrag, aproj);
    k_init<<<(NN + 255) / 256, 256, 0, stream>>>(feat, embed, transform, idx, out, init_bf);
    k_hist<<<(NE + 255) / 256, 256, 0, stream>>>(edge_dst, edge_type, counts50, counts16);
    k_scan<<<1, 1024, 0, stream>>>(counts50, counts16, row_off, c50, toff, tend, c16);
    k_scatter<<<512, 256, 0, stream>>>(edge_src, edge_dst, edge_type,
                                       c16, c50, tsrc, tdst, qa_of_p);
    const int tiles = NEP_MAX / 16;                    // 50016
    k_msg<<<(tiles + 3) / 4, 256, 0, stream>>>(wfrag, afrag, aproj, B_w, B_b,
                                               toff, tend, tsrc, tdst, init_bf, amsg);
    k_agg<<<(NN + 63) / 64, 256, 0, stream>>>(row_off, qa_of_p, amsg, self_w, out);
}

// Round 6
// 274.877 us; speedup vs baseline: 9.1002x; 1.5315x over previous
//
#include <hip/hip_runtime.h>
#include <math.h>

#define NN 50000
#define NE 800000
#define NR 16
#define NEP_MAX (NE + NR * 16)   // type groups padded to multiples of 16
#define NBLK 196                 // ceil(NN/256) scan blocks

typedef __attribute__((ext_vector_type(8))) short short8;
typedef __attribute__((ext_vector_type(4))) float floatx4;

__device__ __forceinline__ unsigned short f2bf(float x) {
    unsigned int u = __float_as_uint(x);
    u += 0x7fffu + ((u >> 16) & 1u);
    return (unsigned short)(u >> 16);
}
__device__ __forceinline__ float bf2f(unsigned short s) {
    return __uint_as_float(((unsigned int)s) << 16);
}

// ---------------------------------------------------------------------------
// K1: build MFMA-fragment-layout weights (bf16) + attention bias
//   wfrag[t][nt][lane][j] = relw[t][k][n],  k=(lane>>4)*8+j, n=(lane&15)+16*nt
//   afrag[ks][nt][lane][j] = A_w[ks*32+k][n]
//   aproj[t][j] = A_b[j] + sum_k attn_emb[t,k]*A_w[64+k, j]
// ---------------------------------------------------------------------------
__global__ void k_prep(const float* __restrict__ weight, const float* __restrict__ w_comp,
                       const float* __restrict__ A_w, const float* __restrict__ A_b,
                       const float* __restrict__ attn_emb,
                       unsigned short* __restrict__ wfrag, unsigned short* __restrict__ afrag,
                       float* __restrict__ aproj) {
    int g = blockIdx.x * blockDim.x + threadIdx.x;
    if (g < 16 * 2 * 64 * 8) {                 // wfrag: 16384 (1024 per type)
        int t = g >> 10, rest = g & 1023;
        int nt = rest >> 9, l = (rest >> 3) & 63, j = rest & 7;
        int k = (l >> 4) * 8 + j, n = (l & 15) + 16 * nt;
        float acc = 0.f;
#pragma unroll
        for (int b = 0; b < 4; b++) acc += w_comp[t * 4 + b] * weight[b * 1024 + k * 32 + n];
        wfrag[g] = f2bf(acc);
    }
    if (g < 2 * 2 * 64 * 8) {                  // afrag: 2048 (1024 per ks)
        int ks = g >> 10, rest = g & 1023;
        int nt = rest >> 9, l = (rest >> 3) & 63, j = rest & 7;
        int k = ks * 32 + (l >> 4) * 8 + j, n = (l & 15) + 16 * nt;
        afrag[g] = f2bf(A_w[k * 32 + n]);
    }
    if (g < 16 * 32) {                         // aproj: 512
        int t = g >> 5, j = g & 31;
        float acc = A_b[j];
#pragma unroll
        for (int k = 0; k < 32; k++) acc += attn_emb[t * 32 + k] * A_w[(64 + k) * 32 + j];
        aproj[g] = acc;
    }
}

// ---------------------------------------------------------------------------
// K2: init_fea = concat(feat, embed[idx]) @ T -> out[:,0,:] (fp32) + bf16 copy
// ---------------------------------------------------------------------------
__global__ void k_init(const float* __restrict__ feat, const float* __restrict__ emb,
                       const float* __restrict__ T, const int* __restrict__ idx,
                       float* __restrict__ out, unsigned short* __restrict__ init_bf) {
    int i = blockIdx.x * blockDim.x + threadIdx.x;
    if (i >= NN) return;
    float v[32], acc[32];
#pragma unroll
    for (int o = 0; o < 32; o++) acc[o] = 0.f;
    const float4* fp = (const float4*)(feat + (size_t)i * 32);
#pragma unroll
    for (int q = 0; q < 8; q++) {
        float4 f = fp[q];
        v[4 * q] = f.x; v[4 * q + 1] = f.y; v[4 * q + 2] = f.z; v[4 * q + 3] = f.w;
    }
#pragma unroll
    for (int d = 0; d < 32; d++) {
        float xd = v[d];
#pragma unroll
        for (int o = 0; o < 32; o++) acc[o] += xd * T[d * 32 + o];
    }
    int row = idx[i];
    const float4* ep = (const float4*)(emb + (size_t)row * 32);
#pragma unroll
    for (int q = 0; q < 8; q++) {
        float4 f = ep[q];
        v[4 * q] = f.x; v[4 * q + 1] = f.y; v[4 * q + 2] = f.z; v[4 * q + 3] = f.w;
    }
#pragma unroll
    for (int d = 0; d < 32; d++) {
        float xd = v[d];
#pragma unroll
        for (int o = 0; o < 32; o++) acc[o] += xd * T[(32 + d) * 32 + o];
    }
    float4* op = (float4*)(out + (size_t)i * 64);
#pragma unroll
    for (int q = 0; q < 8; q++) {
        float4 f;
        f.x = acc[4 * q]; f.y = acc[4 * q + 1]; f.z = acc[4 * q + 2]; f.w = acc[4 * q + 3];
        op[q] = f;
    }
    unsigned int w[16];
#pragma unroll
    for (int q = 0; q < 16; q++)
        w[q] = (unsigned int)f2bf(acc[2 * q]) | ((unsigned int)f2bf(acc[2 * q + 1]) << 16);
    uint4* bp = (uint4*)(init_bf + (size_t)i * 32);
#pragma unroll
    for (int q = 0; q < 4; q++) {
        uint4 u; u.x = w[4 * q]; u.y = w[4 * q + 1]; u.z = w[4 * q + 2]; u.w = w[4 * q + 3];
        bp[q] = u;
    }
}

// ---------------------------------------------------------------------------
// K3: fused histograms: 50K dst bins (global atomics) + 16 type bins (LDS)
// ---------------------------------------------------------------------------
__global__ void k_hist(const int* __restrict__ ed, const int* __restrict__ et,
                       int* __restrict__ counts50, int* __restrict__ counts16) {
    __shared__ int lc[NR];
    if (threadIdx.x < NR) lc[threadIdx.x] = 0;
    __syncthreads();
    int e = blockIdx.x * blockDim.x + threadIdx.x;
    if (e < NE) {
        atomicAdd(&counts50[ed[e]], 1);
        atomicAdd(&lc[et[e]], 1);
    }
    __syncthreads();
    if (threadIdx.x < NR) atomicAdd(&counts16[threadIdx.x], lc[threadIdx.x]);
}

// ---------------------------------------------------------------------------
// K4a/b/c: multi-block scan (replaces the 126us single-block k_scan: one
// block on 256 CUs was pure latency).
// S1: per-block LDS scan of 256 counts -> local-exclusive in row_off + bsum.
// S2: one block scans bsum[NBLK] in place (exclusive) + the 16-bin type scan.
// S3: row_off[i] += bsum[blk]; c50[i] = row_off[i]; row_off[NN] = NE.
// ---------------------------------------------------------------------------
__global__ void __launch_bounds__(256) k_scan1(const int* __restrict__ counts50,
                                               int* __restrict__ row_off,
                                               int* __restrict__ bsum) {
    __shared__ int ls[256];
    int tid = threadIdx.x;
    int i = blockIdx.x * 256 + tid;
    int v = (i < NN) ? counts50[i] : 0;
    ls[tid] = v;
    __syncthreads();
    for (int off = 1; off < 256; off <<= 1) {
        int t = (tid >= off) ? ls[tid - off] : 0;
        __syncthreads();
        ls[tid] += t;
        __syncthreads();
    }
    if (i < NN) row_off[i] = ls[tid] - v;       // local exclusive
    if (tid == 255) bsum[blockIdx.x] = ls[255]; // block total
}

__global__ void __launch_bounds__(256) k_scan2(int* __restrict__ bsum,
                                               const int* __restrict__ counts16,
                                               int* __restrict__ toff, int* __restrict__ tend,
                                               int* __restrict__ c16) {
    __shared__ int ls[256];
    int tid = threadIdx.x;
    int v = (tid < NBLK) ? bsum[tid] : 0;
    ls[tid] = v;
    __syncthreads();
    for (int off = 1; off < 256; off <<= 1) {
        int t = (tid >= off) ? ls[tid - off] : 0;
        __syncthreads();
        ls[tid] += t;
        __syncthreads();
    }
    if (tid < NBLK) bsum[tid] = ls[tid] - v;    // exclusive, in place
    if (tid == 0) {
        int acc = 0;
        for (int t = 0; t < NR; t++) {
            toff[t] = acc;
            c16[t] = acc;
            int c = counts16[t];
            tend[t] = acc + c;
            acc += ((c + 15) >> 4) << 4;        // pad to multiple of 16
        }
        toff[NR] = acc;
    }
}

__global__ void __launch_bounds__(256) k_scan3(int* __restrict__ row_off,
                                               int* __restrict__ c50,
                                               const int* __restrict__ bsum) {
    int i = blockIdx.x * 256 + threadIdx.x;
    if (i < NN) {
        int v = row_off[i] + bsum[blockIdx.x];
        row_off[i] = v;
        c50[i] = v;
    }
    if (i == 0) row_off[NN] = NE;
}

// ---------------------------------------------------------------------------
// K5: scatter with hierarchical type-bin claim (R4 lesson: per-edge global
// atomics on 16 addresses serialize at L2). Records the INVERSE permutation
// p_of_q so k_msg can write amsg directly in dst-sorted order.
// ---------------------------------------------------------------------------
__global__ void k_scatter(const int* __restrict__ es, const int* __restrict__ ed,
                          const int* __restrict__ et, int* __restrict__ c16,
                          int* __restrict__ c50, int* __restrict__ tsrc,
                          int* __restrict__ tdst, int* __restrict__ p_of_q) {
    const int chunk = (NE + gridDim.x - 1) / gridDim.x;
    const int start = blockIdx.x * chunk;
    const int end = min(start + chunk, NE);
    __shared__ int lc[NR], lb[NR];
    if (threadIdx.x < NR) lc[threadIdx.x] = 0;
    __syncthreads();
    for (int e = start + threadIdx.x; e < end; e += blockDim.x)
        atomicAdd(&lc[et[e]], 1);
    __syncthreads();
    if (threadIdx.x < NR) {
        lb[threadIdx.x] = atomicAdd(&c16[threadIdx.x], lc[threadIdx.x]);
        lc[threadIdx.x] = 0;
    }
    __syncthreads();
    for (int e = start + threadIdx.x; e < end; e += blockDim.x) {
        int s = es[e], d = ed[e], t = et[e];
        int q = lb[t] + atomicAdd(&lc[t], 1);
        int p = atomicAdd(&c50[d], 1);
        tsrc[q] = s;
        tdst[q] = d;
        p_of_q[q] = p;
    }
}

// ---------------------------------------------------------------------------
// K6: type-major MFMA kernel. One 16-edge type-pure tile per wave, no LDS.
//   msg = x @ W_t             (2x mfma 16x16x32 bf16)
//   hid = x @ A_w0 + y @ A_w1 (4x mfma) + aproj[t]
//   a = sigmoid(relu(hid) . B_w + B_b)   (16-lane butterfly reduce)
//   amsg[p_of_q[q]] = bf16(a * msg)  -- scattered write, so k_agg streams.
// ---------------------------------------------------------------------------
__global__ void __launch_bounds__(256) k_msg(
    const unsigned short* __restrict__ wfrag, const unsigned short* __restrict__ afrag,
    const float* __restrict__ aproj, const float* __restrict__ B_w,
    const float* __restrict__ B_b, const int* __restrict__ toff,
    const int* __restrict__ tend, const int* __restrict__ tsrc,
    const int* __restrict__ tdst, const int* __restrict__ p_of_q,
    const unsigned short* __restrict__ init_bf, unsigned short* __restrict__ amsg) {
    const int wave = threadIdx.x >> 6;
    const int lane = threadIdx.x & 63;
    const int q0 = (blockIdx.x * 4 + wave) * 16;
    if (q0 >= toff[NR]) return;
    int t = 0;
#pragma unroll
    for (int i = 1; i < NR; i++) t += (q0 >= toff[i]) ? 1 : 0;
    t = __builtin_amdgcn_readfirstlane(t);
    const int te = tend[t];
    const int m = lane & 15, quad = lane >> 4;
    const int qa = q0 + m;
    const bool va = qa < te;
    int src = va ? tsrc[qa] : 0;
    int dst = va ? tdst[qa] : 0;
    short8 xa = *(const short8*)(init_bf + (size_t)src * 32 + quad * 8);
    short8 ya = *(const short8*)(init_bf + (size_t)dst * 32 + quad * 8);
    short8 wb0 = *(const short8*)(wfrag + (size_t)((t * 2 + 0) * 64 + lane) * 8);
    short8 wb1 = *(const short8*)(wfrag + (size_t)((t * 2 + 1) * 64 + lane) * 8);
    short8 a00 = *(const short8*)(afrag + (size_t)((0 * 2 + 0) * 64 + lane) * 8);
    short8 a01 = *(const short8*)(afrag + (size_t)((0 * 2 + 1) * 64 + lane) * 8);
    short8 a10 = *(const short8*)(afrag + (size_t)((1 * 2 + 0) * 64 + lane) * 8);
    short8 a11 = *(const short8*)(afrag + (size_t)((1 * 2 + 1) * 64 + lane) * 8);
    floatx4 z4 = {0.f, 0.f, 0.f, 0.f};
    floatx4 mc0 = __builtin_amdgcn_mfma_f32_16x16x32_bf16(xa, wb0, z4, 0, 0, 0);
    floatx4 mc1 = __builtin_amdgcn_mfma_f32_16x16x32_bf16(xa, wb1, z4, 0, 0, 0);
    floatx4 hc0 = __builtin_amdgcn_mfma_f32_16x16x32_bf16(xa, a00, z4, 0, 0, 0);
    hc0 = __builtin_amdgcn_mfma_f32_16x16x32_bf16(ya, a10, hc0, 0, 0, 0);
    floatx4 hc1 = __builtin_amdgcn_mfma_f32_16x16x32_bf16(xa, a01, z4, 0, 0, 0);
    hc1 = __builtin_amdgcn_mfma_f32_16x16x32_bf16(ya, a11, hc1, 0, 0, 0);
    const int col = m;
    float ap0 = aproj[t * 32 + col], ap1 = aproj[t * 32 + 16 + col];
    float bw0 = B_w[col], bw1 = B_w[col + 16];
    float bb = B_b[0];
    float part[4];
#pragma unroll
    for (int r = 0; r < 4; r++)
        part[r] = fmaxf(hc0[r] + ap0, 0.f) * bw0 + fmaxf(hc1[r] + ap1, 0.f) * bw1;
#pragma unroll
    for (int s = 1; s < 16; s <<= 1) {
#pragma unroll
        for (int r = 0; r < 4; r++) part[r] += __shfl_xor(part[r], s, 64);
    }
#pragma unroll
    for (int r = 0; r < 4; r++) {
        int qe = q0 + quad * 4 + r;
        if (qe < te) {
            int pe = p_of_q[qe];
            float a = 1.f / (1.f + __expf(-(part[r] + bb)));
            amsg[(size_t)pe * 32 + col] = f2bf(a * mc0[r]);
            amsg[(size_t)pe * 32 + col + 16] = f2bf(a * mc1[r]);
        }
    }
}

// ---------------------------------------------------------------------------
// K7: dst-major aggregation + fused self-loop GEMM + ReLU.
// amsg is dst-sorted -> each node's rows are contiguous: pure streaming.
// 4 threads per node (8 cols each).
// ---------------------------------------------------------------------------
__global__ void __launch_bounds__(256) k_agg(
    const int* __restrict__ row_off, const unsigned short* __restrict__ amsg,
    const float* __restrict__ S, float* __restrict__ out) {
    int tid = threadIdx.x;
    int v = blockIdx.x * 64 + (tid >> 2);
    if (v >= NN) return;
    int c0 = (tid & 3) * 8;
    float acc[8];
#pragma unroll
    for (int j = 0; j < 8; j++) acc[j] = 0.f;
    int p0 = row_off[v], p1 = row_off[v + 1];
    for (int p = p0; p < p1; p++) {
        short8 mv = *(const short8*)(amsg + (size_t)p * 32 + c0);
#pragma unroll
        for (int j = 0; j < 8; j++) acc[j] += bf2f((unsigned short)mv[j]);
    }
    float x[32];
    const float4* xp = (const float4*)(out + (size_t)v * 64);
#pragma unroll
    for (int q = 0; q < 8; q++) {
        float4 f = xp[q];
        x[4 * q] = f.x; x[4 * q + 1] = f.y; x[4 * q + 2] = f.z; x[4 * q + 3] = f.w;
    }
#pragma unroll
    for (int d = 0; d < 32; d++) {
        float xd = x[d];
#pragma unroll
        for (int j = 0; j < 8; j++) acc[j] += xd * S[d * 32 + c0 + j];
    }
    float4* op = (float4*)(out + (size_t)v * 64 + 32 + c0);
#pragma unroll
    for (int q = 0; q < 2; q++) {
        float4 f;
        f.x = fmaxf(acc[4 * q], 0.f);
        f.y = fmaxf(acc[4 * q + 1], 0.f);
        f.z = fmaxf(acc[4 * q + 2], 0.f);
        f.w = fmaxf(acc[4 * q + 3], 0.f);
        op[q] = f;
    }
}

extern "C" void kernel_launch(void* const* d_in, const int* in_sizes, int n_in,
                              void* d_out, int out_size, void* d_ws, size_t ws_size,
                              hipStream_t stream) {
    const float* feat      = (const float*)d_in[0];
    const float* embed     = (const float*)d_in[1];
    const float* transform = (const float*)d_in[2];
    const float* weight    = (const float*)d_in[3];
    const float* w_comp    = (const float*)d_in[4];
    const float* self_w    = (const float*)d_in[5];
    const float* A_w       = (const float*)d_in[6];
    const float* A_b       = (const float*)d_in[7];
    const float* B_w       = (const float*)d_in[8];
    const float* B_b       = (const float*)d_in[9];
    const float* attn_emb  = (const float*)d_in[10];
    const int*   idx       = (const int*)d_in[11];
    const int*   edge_src  = (const int*)d_in[12];
    const int*   edge_dst  = (const int*)d_in[13];
    const int*   edge_type = (const int*)d_in[14];
    float* out = (float*)d_out;

    // -------- workspace layout (16B-aligned large arrays first) --------
    char* ws = (char*)d_ws;
    unsigned short* amsg    = (unsigned short*)ws;                 // NEP_MAX*32 us = 51,216,384 B
    unsigned short* init_bf = (unsigned short*)(ws + (size_t)NEP_MAX * 64);          // 3,200,000 B
    unsigned short* wfrag   = (unsigned short*)((char*)init_bf + 3200000);           // 32,768 B
    unsigned short* afrag   = (unsigned short*)((char*)wfrag + 32768);               // 4,096 B
    float*          aproj   = (float*)((char*)afrag + 4096);                         // 2,048 B
    int* ip       = (int*)((char*)aproj + 2048);
    int* toff     = ip;              ip += 32;       // 17 used
    int* tend     = ip;              ip += 16;
    int* c16      = ip;              ip += 16;
    int* bsum     = ip;              ip += 256;      // NBLK used
    int* counts16 = ip;              ip += 16;       // adjacent to counts50 for one memset
    int* counts50 = ip;              ip += NN;
    int* row_off  = ip;              ip += NN + 1;
    int* c50      = ip;              ip += NN;
    int* tsrc     = ip;              ip += NEP_MAX;
    int* tdst     = ip;              ip += NEP_MAX;
    int* p_of_q   = ip;              ip += NEP_MAX;  // total ~64.7 MB

    hipMemsetAsync(counts16, 0, (size_t)(16 + NN) * sizeof(int), stream);

    k_prep<<<(16384 + 255) / 256, 256, 0, stream>>>(weight, w_comp, A_w, A_b, attn_emb,
                                                    wfrag, afrag, aproj);
    k_init<<<(NN + 255) / 256, 256, 0, stream>>>(feat, embed, transform, idx, out, init_bf);
    k_hist<<<(NE + 255) / 256, 256, 0, stream>>>(edge_dst, edge_type, counts50, counts16);
    k_scan1<<<NBLK, 256, 0, stream>>>(counts50, row_off, bsum);
    k_scan2<<<1, 256, 0, stream>>>(bsum, counts16, toff, tend, c16);
    k_scan3<<<NBLK, 256, 0, stream>>>(row_off, c50, bsum);
    k_scatter<<<512, 256, 0, stream>>>(edge_src, edge_dst, edge_type,
                                       c16, c50, tsrc, tdst, p_of_q);
    const int tiles = NEP_MAX / 16;                    // 50016
    k_msg<<<(tiles + 3) / 4, 256, 0, stream>>>(wfrag, afrag, aproj, B_w, B_b,
                                               toff, tend, tsrc, tdst, p_of_q,
                                               init_bf, amsg);
    k_agg<<<(NN + 63) / 64, 256, 0, stream>>>(row_off, amsg, self_w, out);
}

// Round 7
// 212.312 us; speedup vs baseline: 11.7819x; 1.2947x over previous
//
#include <hip/hip_runtime.h>
#include <math.h>

#define NN 50000
#define NE 800000
#define NR 16
#define NEP_MAX (NE + NR * 16)   // type groups padded to multiples of 16
#define NB 196                   // coarse dst buckets (dst>>8), ceil(50000/256)
#define NBIN 212                 // 196 coarse + 16 type bins
#define ABLK 256                 // blocks in count/scatter passes
#define CHUNK ((NE + ABLK - 1) / ABLK)   // 3125

typedef __attribute__((ext_vector_type(8))) short short8;
typedef __attribute__((ext_vector_type(4))) float floatx4;

__device__ __forceinline__ unsigned short f2bf(float x) {
    unsigned int u = __float_as_uint(x);
    u += 0x7fffu + ((u >> 16) & 1u);
    return (unsigned short)(u >> 16);
}
__device__ __forceinline__ float bf2f(unsigned short s) {
    return __uint_as_float(((unsigned int)s) << 16);
}

// ---------------------------------------------------------------------------
// K1: build MFMA-fragment-layout weights (bf16) + attention bias
// ---------------------------------------------------------------------------
__global__ void k_prep(const float* __restrict__ weight, const float* __restrict__ w_comp,
                       const float* __restrict__ A_w, const float* __restrict__ A_b,
                       const float* __restrict__ attn_emb,
                       unsigned short* __restrict__ wfrag, unsigned short* __restrict__ afrag,
                       float* __restrict__ aproj) {
    int g = blockIdx.x * blockDim.x + threadIdx.x;
    if (g < 16 * 2 * 64 * 8) {                 // wfrag: 16384 (1024 per type)
        int t = g >> 10, rest = g & 1023;
        int nt = rest >> 9, l = (rest >> 3) & 63, j = rest & 7;
        int k = (l >> 4) * 8 + j, n = (l & 15) + 16 * nt;
        float acc = 0.f;
#pragma unroll
        for (int b = 0; b < 4; b++) acc += w_comp[t * 4 + b] * weight[b * 1024 + k * 32 + n];
        wfrag[g] = f2bf(acc);
    }
    if (g < 2 * 2 * 64 * 8) {                  // afrag: 2048 (1024 per ks)
        int ks = g >> 10, rest = g & 1023;
        int nt = rest >> 9, l = (rest >> 3) & 63, j = rest & 7;
        int k = ks * 32 + (l >> 4) * 8 + j, n = (l & 15) + 16 * nt;
        afrag[g] = f2bf(A_w[k * 32 + n]);
    }
    if (g < 16 * 32) {                         // aproj: 512
        int t = g >> 5, j = g & 31;
        float acc = A_b[j];
#pragma unroll
        for (int k = 0; k < 32; k++) acc += attn_emb[t * 32 + k] * A_w[(64 + k) * 32 + j];
        aproj[g] = acc;
    }
}

// ---------------------------------------------------------------------------
// K2: init_fea = concat(feat, embed[idx]) @ T -> out[:,0,:] (fp32) + bf16 copy
// ---------------------------------------------------------------------------
__global__ void k_init(const float* __restrict__ feat, const float* __restrict__ emb,
                       const float* __restrict__ T, const int* __restrict__ idx,
                       float* __restrict__ out, unsigned short* __restrict__ init_bf) {
    int i = blockIdx.x * blockDim.x + threadIdx.x;
    if (i >= NN) return;
    float v[32], acc[32];
#pragma unroll
    for (int o = 0; o < 32; o++) acc[o] = 0.f;
    const float4* fp = (const float4*)(feat + (size_t)i * 32);
#pragma unroll
    for (int q = 0; q < 8; q++) {
        float4 f = fp[q];
        v[4 * q] = f.x; v[4 * q + 1] = f.y; v[4 * q + 2] = f.z; v[4 * q + 3] = f.w;
    }
#pragma unroll
    for (int d = 0; d < 32; d++) {
        float xd = v[d];
#pragma unroll
        for (int o = 0; o < 32; o++) acc[o] += xd * T[d * 32 + o];
    }
    int row = idx[i];
    const float4* ep = (const float4*)(emb + (size_t)row * 32);
#pragma unroll
    for (int q = 0; q < 8; q++) {
        float4 f = ep[q];
        v[4 * q] = f.x; v[4 * q + 1] = f.y; v[4 * q + 2] = f.z; v[4 * q + 3] = f.w;
    }
#pragma unroll
    for (int d = 0; d < 32; d++) {
        float xd = v[d];
#pragma unroll
        for (int o = 0; o < 32; o++) acc[o] += xd * T[(32 + d) * 32 + o];
    }
    float4* op = (float4*)(out + (size_t)i * 64);
#pragma unroll
    for (int q = 0; q < 8; q++) {
        float4 f;
        f.x = acc[4 * q]; f.y = acc[4 * q + 1]; f.z = acc[4 * q + 2]; f.w = acc[4 * q + 3];
        op[q] = f;
    }
    unsigned int w[16];
#pragma unroll
    for (int q = 0; q < 16; q++)
        w[q] = (unsigned int)f2bf(acc[2 * q]) | ((unsigned int)f2bf(acc[2 * q + 1]) << 16);
    uint4* bp = (uint4*)(init_bf + (size_t)i * 32);
#pragma unroll
    for (int q = 0; q < 4; q++) {
        uint4 u; u.x = w[4 * q]; u.y = w[4 * q + 1]; u.z = w[4 * q + 2]; u.w = w[4 * q + 3];
        bp[q] = u;
    }
}

// ---------------------------------------------------------------------------
// K3: per-block LDS histogram of coarse dst bucket (dst>>8) + type bins.
// Plain stores of per-block counts — ZERO global atomics (the R6 lesson:
// every global atomic write-throughs 32 B to HBM; 800K of them = 55 us).
// ---------------------------------------------------------------------------
__global__ void __launch_bounds__(256) k_count(const int* __restrict__ ed,
                                               const int* __restrict__ et,
                                               int* __restrict__ cpb) {
    __shared__ int lc[NBIN];
    for (int i = threadIdx.x; i < NBIN; i += 256) lc[i] = 0;
    __syncthreads();
    const int start = blockIdx.x * CHUNK, end = min(start + CHUNK, NE);
    for (int e = start + threadIdx.x; e < end; e += 256) {
        atomicAdd(&lc[ed[e] >> 8], 1);
        atomicAdd(&lc[NB + et[e]], 1);
    }
    __syncthreads();
    for (int i = threadIdx.x; i < NBIN; i += 256) cpb[blockIdx.x * NBIN + i] = lc[i];
}

// ---------------------------------------------------------------------------
// K4: single-block scan. Per bin: prefix over the 256 blocks (in-place in cpb
// -> per-block RELATIVE cursors). Then totals -> boff (coarse, 197 entries)
// and toff/tend (type bins padded to multiples of 16).
// ---------------------------------------------------------------------------
__global__ void __launch_bounds__(256) k_scanB(int* __restrict__ cpb,
                                               int* __restrict__ boff,
                                               int* __restrict__ toff,
                                               int* __restrict__ tend) {
    __shared__ int tot[NBIN];
    int bin = threadIdx.x;
    if (bin < NBIN) {
        int run = 0;
        for (int c = 0; c < ABLK; c++) {
            int v = cpb[c * NBIN + bin];
            cpb[c * NBIN + bin] = run;
            run += v;
        }
        tot[bin] = run;
    }
    __syncthreads();
    if (threadIdx.x == 0) {
        int acc = 0;
        for (int b = 0; b < NB; b++) { boff[b] = acc; acc += tot[b]; }
        boff[NB] = acc;                          // == NE
        int t0 = 0;
        for (int t = 0; t < NR; t++) {
            toff[t] = t0;
            tend[t] = t0 + tot[NB + t];
            t0 += ((tot[NB + t] + 15) >> 4) << 4;
        }
        toff[NR] = t0;
    }
}

// ---------------------------------------------------------------------------
// K5: scatter with precomputed cursors (LDS atomics only). Assigns both the
// type-sorted slot q (-> tsrc/tdst for k_msg) and the coarse-bucket slot
// (-> bpack = (q<<8)|(dst&255) for the fine sort).
// ---------------------------------------------------------------------------
__global__ void __launch_bounds__(256) k_scatA(const int* __restrict__ es,
                                               const int* __restrict__ ed,
                                               const int* __restrict__ et,
                                               const int* __restrict__ cpb,
                                               const int* __restrict__ boff,
                                               const int* __restrict__ toff,
                                               int* __restrict__ tsrc,
                                               int* __restrict__ tdst,
                                               int* __restrict__ bpack) {
    __shared__ int cur[NBIN];
    const int start = blockIdx.x * CHUNK, end = min(start + CHUNK, NE);
    for (int i = threadIdx.x; i < NBIN; i += 256) {
        int base = (i < NB) ? boff[i] : toff[i - NB];
        cur[i] = base + cpb[blockIdx.x * NBIN + i];
    }
    __syncthreads();
    for (int e = start + threadIdx.x; e < end; e += 256) {
        int s = es[e], d = ed[e], t = et[e];
        int q = atomicAdd(&cur[NB + t], 1);
        int slot = atomicAdd(&cur[d >> 8], 1);
        tsrc[q] = s;
        tdst[q] = d;
        bpack[slot] = (q << 8) | (d & 255);
    }
}

// ---------------------------------------------------------------------------
// K6: fine counting sort within each 256-node bucket (one block per bucket).
// Produces row_off (CSR by dst) and the permutation p_of_q so k_msg can
// write amsg directly in dst-sorted order. LDS atomics only.
// ---------------------------------------------------------------------------
__global__ void __launch_bounds__(256) k_fine(const int* __restrict__ boff,
                                              const int* __restrict__ bpack,
                                              int* __restrict__ row_off,
                                              int* __restrict__ p_of_q) {
    __shared__ int h[256], ls[256];
    const int b = blockIdx.x;
    const int s0 = boff[b], s1 = boff[b + 1];
    const int tid = threadIdx.x;
    h[tid] = 0;
    __syncthreads();
    for (int s = s0 + tid; s < s1; s += 256)
        atomicAdd(&h[bpack[s] & 255], 1);
    __syncthreads();
    int v = h[tid];
    ls[tid] = v;
    __syncthreads();
    for (int off = 1; off < 256; off <<= 1) {
        int t = (tid >= off) ? ls[tid - off] : 0;
        __syncthreads();
        ls[tid] += t;
        __syncthreads();
    }
    int excl = ls[tid] - v;                  // exclusive prefix of fine bins
    int node = b * 256 + tid;
    if (node <= NN) row_off[node] = s0 + excl;  // covers row_off[NN]=NE too
    h[tid] = s0 + excl;                      // reuse h as global-position cursor
    __syncthreads();
    for (int s = s0 + tid; s < s1; s += 256) {
        int pk = bpack[s];
        int p = atomicAdd(&h[pk & 255], 1);
        p_of_q[pk >> 8] = p;
    }
}

// ---------------------------------------------------------------------------
// K7: type-major MFMA kernel. One 16-edge type-pure tile per wave, no LDS.
//   msg = x @ W_t; hid = x @ A_w0 + y @ A_w1 + aproj[t]
//   a = sigmoid(relu(hid) . B_w + B_b); amsg[p_of_q[q]] = bf16(a * msg)
// ---------------------------------------------------------------------------
__global__ void __launch_bounds__(256) k_msg(
    const unsigned short* __restrict__ wfrag, const unsigned short* __restrict__ afrag,
    const float* __restrict__ aproj, const float* __restrict__ B_w,
    const float* __restrict__ B_b, const int* __restrict__ toff,
    const int* __restrict__ tend, const int* __restrict__ tsrc,
    const int* __restrict__ tdst, const int* __restrict__ p_of_q,
    const unsigned short* __restrict__ init_bf, unsigned short* __restrict__ amsg) {
    const int wave = threadIdx.x >> 6;
    const int lane = threadIdx.x & 63;
    const int q0 = (blockIdx.x * 4 + wave) * 16;
    if (q0 >= toff[NR]) return;
    int t = 0;
#pragma unroll
    for (int i = 1; i < NR; i++) t += (q0 >= toff[i]) ? 1 : 0;
    t = __builtin_amdgcn_readfirstlane(t);
    const int te = tend[t];
    const int m = lane & 15, quad = lane >> 4;
    const int qa = q0 + m;
    const bool va = qa < te;
    int src = va ? tsrc[qa] : 0;
    int dst = va ? tdst[qa] : 0;
    short8 xa = *(const short8*)(init_bf + (size_t)src * 32 + quad * 8);
    short8 ya = *(const short8*)(init_bf + (size_t)dst * 32 + quad * 8);
    short8 wb0 = *(const short8*)(wfrag + (size_t)((t * 2 + 0) * 64 + lane) * 8);
    short8 wb1 = *(const short8*)(wfrag + (size_t)((t * 2 + 1) * 64 + lane) * 8);
    short8 a00 = *(const short8*)(afrag + (size_t)((0 * 2 + 0) * 64 + lane) * 8);
    short8 a01 = *(const short8*)(afrag + (size_t)((0 * 2 + 1) * 64 + lane) * 8);
    short8 a10 = *(const short8*)(afrag + (size_t)((1 * 2 + 0) * 64 + lane) * 8);
    short8 a11 = *(const short8*)(afrag + (size_t)((1 * 2 + 1) * 64 + lane) * 8);
    floatx4 z4 = {0.f, 0.f, 0.f, 0.f};
    floatx4 mc0 = __builtin_amdgcn_mfma_f32_16x16x32_bf16(xa, wb0, z4, 0, 0, 0);
    floatx4 mc1 = __builtin_amdgcn_mfma_f32_16x16x32_bf16(xa, wb1, z4, 0, 0, 0);
    floatx4 hc0 = __builtin_amdgcn_mfma_f32_16x16x32_bf16(xa, a00, z4, 0, 0, 0);
    hc0 = __builtin_amdgcn_mfma_f32_16x16x32_bf16(ya, a10, hc0, 0, 0, 0);
    floatx4 hc1 = __builtin_amdgcn_mfma_f32_16x16x32_bf16(xa, a01, z4, 0, 0, 0);
    hc1 = __builtin_amdgcn_mfma_f32_16x16x32_bf16(ya, a11, hc1, 0, 0, 0);
    const int col = m;
    float ap0 = aproj[t * 32 + col], ap1 = aproj[t * 32 + 16 + col];
    float bw0 = B_w[col], bw1 = B_w[col + 16];
    float bb = B_b[0];
    float part[4];
#pragma unroll
    for (int r = 0; r < 4; r++)
        part[r] = fmaxf(hc0[r] + ap0, 0.f) * bw0 + fmaxf(hc1[r] + ap1, 0.f) * bw1;
#pragma unroll
    for (int s = 1; s < 16; s <<= 1) {
#pragma unroll
        for (int r = 0; r < 4; r++) part[r] += __shfl_xor(part[r], s, 64);
    }
#pragma unroll
    for (int r = 0; r < 4; r++) {
        int qe = q0 + quad * 4 + r;
        if (qe < te) {
            int pe = p_of_q[qe];
            float a = 1.f / (1.f + __expf(-(part[r] + bb)));
            amsg[(size_t)pe * 32 + col] = f2bf(a * mc0[r]);
            amsg[(size_t)pe * 32 + col + 16] = f2bf(a * mc1[r]);
        }
    }
}

// ---------------------------------------------------------------------------
// K8: dst-major aggregation + fused self-loop GEMM + ReLU (streaming amsg).
// ---------------------------------------------------------------------------
__global__ void __launch_bounds__(256) k_agg(
    const int* __restrict__ row_off, const unsigned short* __restrict__ amsg,
    const float* __restrict__ S, float* __restrict__ out) {
    int tid = threadIdx.x;
    int v = blockIdx.x * 64 + (tid >> 2);
    if (v >= NN) return;
    int c0 = (tid & 3) * 8;
    float acc[8];
#pragma unroll
    for (int j = 0; j < 8; j++) acc[j] = 0.f;
    int p0 = row_off[v], p1 = row_off[v + 1];
    for (int p = p0; p < p1; p++) {
        short8 mv = *(const short8*)(amsg + (size_t)p * 32 + c0);
#pragma unroll
        for (int j = 0; j < 8; j++) acc[j] += bf2f((unsigned short)mv[j]);
    }
    float x[32];
    const float4* xp = (const float4*)(out + (size_t)v * 64);
#pragma unroll
    for (int q = 0; q < 8; q++) {
        float4 f = xp[q];
        x[4 * q] = f.x; x[4 * q + 1] = f.y; x[4 * q + 2] = f.z; x[4 * q + 3] = f.w;
    }
#pragma unroll
    for (int d = 0; d < 32; d++) {
        float xd = x[d];
#pragma unroll
        for (int j = 0; j < 8; j++) acc[j] += xd * S[d * 32 + c0 + j];
    }
    float4* op = (float4*)(out + (size_t)v * 64 + 32 + c0);
#pragma unroll
    for (int q = 0; q < 2; q++) {
        float4 f;
        f.x = fmaxf(acc[4 * q], 0.f);
        f.y = fmaxf(acc[4 * q + 1], 0.f);
        f.z = fmaxf(acc[4 * q + 2], 0.f);
        f.w = fmaxf(acc[4 * q + 3], 0.f);
        op[q] = f;
    }
}

extern "C" void kernel_launch(void* const* d_in, const int* in_sizes, int n_in,
                              void* d_out, int out_size, void* d_ws, size_t ws_size,
                              hipStream_t stream) {
    const float* feat      = (const float*)d_in[0];
    const float* embed     = (const float*)d_in[1];
    const float* transform = (const float*)d_in[2];
    const float* weight    = (const float*)d_in[3];
    const float* w_comp    = (const float*)d_in[4];
    const float* self_w    = (const float*)d_in[5];
    const float* A_w       = (const float*)d_in[6];
    const float* A_b       = (const float*)d_in[7];
    const float* B_w       = (const float*)d_in[8];
    const float* B_b       = (const float*)d_in[9];
    const float* attn_emb  = (const float*)d_in[10];
    const int*   idx       = (const int*)d_in[11];
    const int*   edge_src  = (const int*)d_in[12];
    const int*   edge_dst  = (const int*)d_in[13];
    const int*   edge_type = (const int*)d_in[14];
    float* out = (float*)d_out;

    // -------- workspace layout --------
    char* ws = (char*)d_ws;
    unsigned short* amsg    = (unsigned short*)ws;                 // NEP_MAX*64 B = 51,216,384
    int*            bpack   = (int*)ws;      // aliases amsg[0 .. NE*4B): consumed by k_fine
                                             // BEFORE k_msg overwrites the region.
    unsigned short* init_bf = (unsigned short*)(ws + (size_t)NEP_MAX * 64);          // 3,200,000 B
    unsigned short* wfrag   = (unsigned short*)((char*)init_bf + 3200000);           // 32,768 B
    unsigned short* afrag   = (unsigned short*)((char*)wfrag + 32768);               // 4,096 B
    float*          aproj   = (float*)((char*)afrag + 4096);                         // 2,048 B
    int* ip       = (int*)((char*)aproj + 2048);
    int* toff     = ip;              ip += 32;          // 17 used
    int* tend     = ip;              ip += 16;
    int* boff     = ip;              ip += 200;         // 197 used
    int* cpb      = ip;              ip += ABLK * NBIN; // 54,272
    int* row_off  = ip;              ip += NN + 1;
    int* tsrc     = ip;              ip += NEP_MAX;
    int* tdst     = ip;              ip += NEP_MAX;
    int* p_of_q   = ip;              ip += NEP_MAX;     // total ~64.5 MB

    k_prep<<<(16384 + 255) / 256, 256, 0, stream>>>(weight, w_comp, A_w, A_b, attn_emb,
                                                    wfrag, afrag, aproj);
    k_init<<<(NN + 255) / 256, 256, 0, stream>>>(feat, embed, transform, idx, out, init_bf);
    k_count<<<ABLK, 256, 0, stream>>>(edge_dst, edge_type, cpb);
    k_scanB<<<1, 256, 0, stream>>>(cpb, boff, toff, tend);
    k_scatA<<<ABLK, 256, 0, stream>>>(edge_src, edge_dst, edge_type, cpb, boff, toff,
                                      tsrc, tdst, bpack);
    k_fine<<<NB, 256, 0, stream>>>(boff, bpack, row_off, p_of_q);
    const int tiles = NEP_MAX / 16;                    // 50016
    k_msg<<<(tiles + 3) / 4, 256, 0, stream>>>(wfrag, afrag, aproj, B_w, B_b,
                                               toff, tend, tsrc, tdst, p_of_q,
                                               init_bf, amsg);
    k_agg<<<(NN + 63) / 64, 256, 0, stream>>>(row_off, amsg, self_w, out);
}